// Round 9
// baseline (132.581 us; speedup 1.0000x reference)
//
#include <hip/hip_runtime.h>
#include <hip/hip_bf16.h>

#define NN 2048
typedef unsigned short u16;
typedef unsigned long long u64;
typedef __attribute__((ext_vector_type(8))) short short8;
typedef __attribute__((ext_vector_type(4))) float f32x4;
typedef __attribute__((ext_vector_type(4))) unsigned u32x4;

// fp32 -> bf16 bits, RNE
__device__ __forceinline__ unsigned bfb(float x) {
    unsigned u = __float_as_uint(x);
    return (u + 0x7FFFu + ((u >> 16) & 1u)) >> 16;
}
__device__ __forceinline__ unsigned pk2(float a, float b) { return bfb(a) | (bfb(b) << 16); }

// ---------------- prep: adj bitmask + bf16 conversions (x, W1^T, W2^T), one dispatch ----------------
__global__ __launch_bounds__(256) void prep(const float* __restrict__ x,
                                            const float* __restrict__ W1,
                                            const float* __restrict__ W2,
                                            const int* __restrict__ adj,
                                            u16* __restrict__ xb, u16* __restrict__ w1t,
                                            u16* __restrict__ w2t, u64* __restrict__ ab) {
    const int b = blockIdx.x;
    if (b < 16384) {                         // adj bits
        int t = b * 256 + threadIdx.x;
        int W = t >> 6, lane = t & 63;
        int i = W >> 5, jw = W & 31;
        int a = adj[(size_t)i * NN + jw * 64 + lane];
        u64 m = __ballot(a != 0);
        if (lane == 0) ab[(size_t)i * 32 + jw] = m;
    } else if (b < 16384 + 1024) {           // x: 2048x512 -> bf16
        int t = (b - 16384) * 256 + threadIdx.x;
        float4 v = ((const float4*)x)[t];
        uint2 o;
        o.x = pk2(v.x, v.y);
        o.y = pk2(v.z, v.w);
        ((uint2*)xb)[t] = o;
    } else if (b < 16384 + 1024 + 512) {     // w1t[c][k] = W1[k][c]
        int u = (b - 17408) * 256 + threadIdx.x;
        int c = u >> 9, k = u & 511;
        w1t[u] = (u16)bfb(W1[(size_t)k * 256 + c]);
    } else {                                 // w2t[c][k] = W2[k][c]
        int u = (b - 17920) * 256 + threadIdx.x;
        int c = u >> 8, k = u & 255;
        w2t[u] = (u16)bfb(W2[(size_t)k * 128 + c]);
    }
}

// ---------------- gemm1: 16 rows x 32 cols (= head cs), K-split-2; el/ert in epilogue ----------------
__global__ __launch_bounds__(256) void gemm1(const u16* __restrict__ A,   // [2048][512]
                                             const u16* __restrict__ BT,  // [256][512]
                                             const float* __restrict__ al,
                                             const float* __restrict__ ar,
                                             u16* __restrict__ GT,        // [256][2048]
                                             float* __restrict__ el,      // [2048][8]
                                             float* __restrict__ ert) {   // [8][2048]
    const int i0 = blockIdx.x * 16, cs = blockIdx.y;
    const int t = threadIdx.x, lane = t & 63, w = t >> 6;
    const int q = lane >> 4, n = lane & 15;
    const int ct = w & 1, kh = w >> 1;
    __shared__ float osh[2][16][16];
    __shared__ float pel[2][16], per_[2][16];

    const u16* ap = A + (size_t)(i0 + n) * 512 + kh * 256 + q * 8;
    const u16* bp = BT + (size_t)(cs * 32 + ct * 16 + n) * 512 + kh * 256 + q * 8;
    f32x4 acc = {0.f, 0.f, 0.f, 0.f};
#pragma unroll
    for (int ks = 0; ks < 8; ++ks) {
        short8 a = *(const short8*)(ap + ks * 32);
        short8 b = *(const short8*)(bp + ks * 32);
        acc = __builtin_amdgcn_mfma_f32_16x16x32_bf16(a, b, acc, 0, 0, 0);
    }
    if (kh == 1) {
#pragma unroll
        for (int r = 0; r < 4; ++r) osh[ct][q * 4 + r][n] = acc[r];
    }
    __syncthreads();
    if (kh == 0) {
#pragma unroll
        for (int r = 0; r < 4; ++r) acc[r] += osh[ct][q * 4 + r][n];
        uint2 g0;
        g0.x = pk2(acc[0], acc[1]);
        g0.y = pk2(acc[2], acc[3]);
        *(uint2*)&GT[(size_t)(cs * 32 + ct * 16 + n) * NN + i0 + q * 4] = g0;
        const float alv = al[ct * 16 + n], arv = ar[ct * 16 + n];
#pragma unroll
        for (int r = 0; r < 4; ++r) {
            float ve = acc[r] * alv, vr = acc[r] * arv;
#pragma unroll
            for (int off = 1; off <= 8; off <<= 1) {
                ve += __shfl_xor(ve, off);
                vr += __shfl_xor(vr, off);
            }
            if (n == 0) { pel[ct][q * 4 + r] = ve; per_[ct][q * 4 + r] = vr; }
        }
    }
    __syncthreads();
    if (t < 16) {
        el[(size_t)(i0 + t) * 8 + cs] = pel[0][t] + pel[1][t];
        ert[(size_t)cs * NN + i0 + t] = per_[0][t] + per_[1][t];
    }
}

// ---------------- gemm2: 16 rows x 32 cols of 128, K-split-2; el/ert partials via atomicAdd ----------------
__global__ __launch_bounds__(256) void gemm2(const u16* __restrict__ A,   // [2048][256]
                                             const u16* __restrict__ BT,  // [128][256]
                                             const float* __restrict__ al,
                                             const float* __restrict__ ar,
                                             u16* __restrict__ GT,        // [128][2048]
                                             float* __restrict__ el,      // [2048] (zeroed)
                                             float* __restrict__ ert) {   // [2048] (zeroed)
    const int i0 = blockIdx.x * 16, cs = blockIdx.y;
    const int t = threadIdx.x, lane = t & 63, w = t >> 6;
    const int q = lane >> 4, n = lane & 15;
    const int ct = w & 1, kh = w >> 1;
    __shared__ float osh[2][16][16];
    __shared__ float pel[2][16], per_[2][16];

    const u16* ap = A + (size_t)(i0 + n) * 256 + kh * 128 + q * 8;
    const u16* bp = BT + (size_t)(cs * 32 + ct * 16 + n) * 256 + kh * 128 + q * 8;
    f32x4 acc = {0.f, 0.f, 0.f, 0.f};
#pragma unroll
    for (int ks = 0; ks < 4; ++ks) {
        short8 a = *(const short8*)(ap + ks * 32);
        short8 b = *(const short8*)(bp + ks * 32);
        acc = __builtin_amdgcn_mfma_f32_16x16x32_bf16(a, b, acc, 0, 0, 0);
    }
    if (kh == 1) {
#pragma unroll
        for (int r = 0; r < 4; ++r) osh[ct][q * 4 + r][n] = acc[r];
    }
    __syncthreads();
    if (kh == 0) {
#pragma unroll
        for (int r = 0; r < 4; ++r) acc[r] += osh[ct][q * 4 + r][n];
        uint2 g0;
        g0.x = pk2(acc[0], acc[1]);
        g0.y = pk2(acc[2], acc[3]);
        *(uint2*)&GT[(size_t)(cs * 32 + ct * 16 + n) * NN + i0 + q * 4] = g0;
        const float alv = al[cs * 32 + ct * 16 + n], arv = ar[cs * 32 + ct * 16 + n];
#pragma unroll
        for (int r = 0; r < 4; ++r) {
            float ve = acc[r] * alv, vr = acc[r] * arv;
#pragma unroll
            for (int off = 1; off <= 8; off <<= 1) {
                ve += __shfl_xor(ve, off);
                vr += __shfl_xor(vr, off);
            }
            if (n == 0) { pel[ct][q * 4 + r] = ve; per_[ct][q * 4 + r] = vr; }
        }
    }
    __syncthreads();
    if (t < 16) {
        atomicAdd(&el[i0 + t], pel[0][t] + pel[1][t]);
        atomicAdd(&ert[i0 + t], per_[0][t] + per_[1][t]);
    }
}

// ---------------- attn1: 16 rows x 2 heads (64 cols), barrier-free K-loop ----------------
// grid (128,4) x 512 thr = 8 waves; wave w owns K-slice [w*256, w*256+256).
// Each lane (q,n) computes its own A-frag: p[row=n][k=q*8+jj] for 2 heads, 4 MFMAs/chunk.
// Partial acc + psum combined across waves via LDS once at the end.
__global__ __launch_bounds__(512, 2) void attn1(const float* __restrict__ el,      // [2048][8]
                                                const float* __restrict__ ert,     // [8][2048]
                                                const unsigned* __restrict__ ab32, // [2048][64]
                                                const u16* __restrict__ gbt,       // [256][2048]
                                                u16* __restrict__ hbb) {           // [2048][256]
    const int rt = blockIdx.x, sec = blockIdx.y;
    const int i0 = rt * 16, h0 = sec * 2, col0 = sec * 64;
    const int t = threadIdx.x, lane = t & 63, w = t >> 6;
    const int q = lane >> 4, n = lane & 15;

    __shared__ u16 ersb[2][2048];         // bf16 er per head
    __shared__ unsigned absh[16][65];     // padded: bits read was 16-way bank-conflicted
    __shared__ float osh[8][4][16][17];   // per-wave partial C
    __shared__ float pssh[8][16][2];      // per-wave partial psum
    __shared__ float wmax[2][8];
    __shared__ float mxsh[2];

    float4 v0 = *(const float4*)(ert + (size_t)h0 * NN + t * 4);
    float4 v1 = *(const float4*)(ert + (size_t)(h0 + 1) * NN + t * 4);
    uint2 c0, c1;
    c0.x = pk2(v0.x, v0.y); c0.y = pk2(v0.z, v0.w);
    c1.x = pk2(v1.x, v1.y); c1.y = pk2(v1.z, v1.w);
    *(uint2*)&ersb[0][t * 4] = c0;
    *(uint2*)&ersb[1][t * 4] = c1;
    float m0 = fmaxf(fmaxf(v0.x, v0.y), fmaxf(v0.z, v0.w));
    float m1 = fmaxf(fmaxf(v1.x, v1.y), fmaxf(v1.z, v1.w));
#pragma unroll
    for (int off = 32; off; off >>= 1) {
        m0 = fmaxf(m0, __shfl_xor(m0, off));
        m1 = fmaxf(m1, __shfl_xor(m1, off));
    }
    if (lane == 0) { wmax[0][w] = m0; wmax[1][w] = m1; }
    for (int c = t; c < 1024; c += 512)
        absh[c >> 6][c & 63] = ab32[(size_t)(i0 + (c >> 6)) * 64 + (c & 63)];
    __syncthreads();
    if (t < 2) {
        float mm = wmax[t][0];
#pragma unroll
        for (int ww = 1; ww < 8; ++ww) mm = fmaxf(mm, wmax[t][ww]);
        mxsh[t] = mm;
    }
    __syncthreads();

    float elv[2], mxv[2], ps[2];
#pragma unroll
    for (int h = 0; h < 2; ++h) {
        float e = el[(size_t)(i0 + n) * 8 + h0 + h];
        elv[h] = e;
        float mm = e + mxsh[h];
        mxv[h] = fmaxf(mm, 0.2f * mm);
        ps[h] = 0.f;
    }
    f32x4 acc[4];
#pragma unroll
    for (int ct = 0; ct < 4; ++ct) acc[ct] = (f32x4){0.f, 0.f, 0.f, 0.f};

    const int kb = w * 256;
    const u16* gbp = gbt + (size_t)(col0 + n) * NN + kb + q * 8;

#pragma unroll
    for (int ck = 0; ck < 8; ++ck) {
        const int jb = ck * 32;
        unsigned word = absh[n][(kb + jb) >> 5];
        unsigned bits = (word >> (q * 8)) & 0xFFu;
        short8 bv0 = *(const short8*)(gbp + jb);
        short8 bv1 = *(const short8*)(gbp + 16 * NN + jb);
        short8 bv2 = *(const short8*)(gbp + 32 * NN + jb);
        short8 bv3 = *(const short8*)(gbp + 48 * NN + jb);
        short8 af[2];
#pragma unroll
        for (int h = 0; h < 2; ++h) {
            u32x4 raw = *(const u32x4*)&ersb[h][kb + jb + q * 8];
            u32x4 au;
#pragma unroll
            for (int pr = 0; pr < 4; ++pr) {
                unsigned u = raw[pr];
                float e0 = __uint_as_float(u << 16);
                float e1 = __uint_as_float(u & 0xFFFF0000u);
                float s0 = elv[h] + e0, s1 = elv[h] + e1;
                s0 = fmaxf(s0, 0.2f * s0) - mxv[h];
                s1 = fmaxf(s1, 0.2f * s1) - mxv[h];
                float p0 = __expf(s0), p1 = __expf(s1);
                p0 = ((bits >> (2 * pr)) & 1u) ? p0 : 0.f;
                p1 = ((bits >> (2 * pr + 1)) & 1u) ? p1 : 0.f;
                // truncate to bf16 for BOTH psum and MFMA (ratio stays consistent)
                unsigned b0 = __float_as_uint(p0) & 0xFFFF0000u;
                unsigned b1 = __float_as_uint(p1) & 0xFFFF0000u;
                ps[h] += __uint_as_float(b0) + __uint_as_float(b1);
                au[pr] = __builtin_amdgcn_perm(__float_as_uint(p1), __float_as_uint(p0), 0x07060302u);
            }
            af[h] = __builtin_bit_cast(short8, au);
        }
        acc[0] = __builtin_amdgcn_mfma_f32_16x16x32_bf16(af[0], bv0, acc[0], 0, 0, 0);
        acc[1] = __builtin_amdgcn_mfma_f32_16x16x32_bf16(af[0], bv1, acc[1], 0, 0, 0);
        acc[2] = __builtin_amdgcn_mfma_f32_16x16x32_bf16(af[1], bv2, acc[2], 0, 0, 0);
        acc[3] = __builtin_amdgcn_mfma_f32_16x16x32_bf16(af[1], bv3, acc[3], 0, 0, 0);
    }

#pragma unroll
    for (int h = 0; h < 2; ++h) {
        float v = ps[h];
        v += __shfl_xor(v, 16);
        v += __shfl_xor(v, 32);
        if (q == 0) pssh[w][n][h] = v;
    }
#pragma unroll
    for (int ct = 0; ct < 4; ++ct)
#pragma unroll
        for (int r = 0; r < 4; ++r) osh[w][ct][q * 4 + r][n] = acc[ct][r];
    __syncthreads();

    for (int idx = t; idx < 1024; idx += 512) {
        int ct = idx >> 8, mm = (idx >> 4) & 15, nn = idx & 15;
        int hh = ct >> 1;
        float o = 0.f, pv = 0.f;
#pragma unroll
        for (int ww = 0; ww < 8; ++ww) { o += osh[ww][ct][mm][nn]; pv += pssh[ww][mm][hh]; }
        o /= pv;
        o = o > 0.f ? o : (__expf(o) - 1.f); // ELU
        hbb[(size_t)(i0 + mm) * 256 + col0 + ct * 16 + nn] = (u16)bfb(o);
    }
}

// ---------------- attn2: 16 rows x 64 cols (1 head), barrier-free K-loop ----------------
// grid (128,2) x 512 thr; wave K-slice 256 j; 4 col-tiles per wave; fp32 out.
__global__ __launch_bounds__(512, 2) void attn2(const float* __restrict__ el,      // [2048]
                                                const float* __restrict__ ert,     // [2048]
                                                const unsigned* __restrict__ ab32,
                                                const u16* __restrict__ gbt,       // [128][2048]
                                                float* __restrict__ out) {         // [2048][128]
    const int rt = blockIdx.x, sec = blockIdx.y;
    const int i0 = rt * 16, col0 = sec * 64;
    const int t = threadIdx.x, lane = t & 63, w = t >> 6;
    const int q = lane >> 4, n = lane & 15;

    __shared__ u16 ersb[2048];
    __shared__ unsigned absh[16][65];
    __shared__ float osh[8][4][16][17];
    __shared__ float pssh[8][16];
    __shared__ float wmax[8];
    __shared__ float mxsh;

    float4 v0 = *(const float4*)(ert + t * 4);
    uint2 c0;
    c0.x = pk2(v0.x, v0.y); c0.y = pk2(v0.z, v0.w);
    *(uint2*)&ersb[t * 4] = c0;
    float m0 = fmaxf(fmaxf(v0.x, v0.y), fmaxf(v0.z, v0.w));
#pragma unroll
    for (int off = 32; off; off >>= 1) m0 = fmaxf(m0, __shfl_xor(m0, off));
    if (lane == 0) wmax[w] = m0;
    for (int c = t; c < 1024; c += 512)
        absh[c >> 6][c & 63] = ab32[(size_t)(i0 + (c >> 6)) * 64 + (c & 63)];
    __syncthreads();
    if (t == 0) {
        float mm = wmax[0];
#pragma unroll
        for (int ww = 1; ww < 8; ++ww) mm = fmaxf(mm, wmax[ww]);
        mxsh = mm;
    }
    __syncthreads();

    const float elv = el[i0 + n];
    float mm2 = elv + mxsh;
    const float mxv = fmaxf(mm2, 0.2f * mm2);
    float ps = 0.f;
    f32x4 acc[4];
#pragma unroll
    for (int ct = 0; ct < 4; ++ct) acc[ct] = (f32x4){0.f, 0.f, 0.f, 0.f};

    const int kb = w * 256;
    const u16* gbp = gbt + (size_t)(col0 + n) * NN + kb + q * 8;

#pragma unroll
    for (int ck = 0; ck < 8; ++ck) {
        const int jb = ck * 32;
        unsigned word = absh[n][(kb + jb) >> 5];
        unsigned bits = (word >> (q * 8)) & 0xFFu;
        short8 bv0 = *(const short8*)(gbp + jb);
        short8 bv1 = *(const short8*)(gbp + 16 * NN + jb);
        short8 bv2 = *(const short8*)(gbp + 32 * NN + jb);
        short8 bv3 = *(const short8*)(gbp + 48 * NN + jb);
        u32x4 raw = *(const u32x4*)&ersb[kb + jb + q * 8];
        u32x4 au;
#pragma unroll
        for (int pr = 0; pr < 4; ++pr) {
            unsigned u = raw[pr];
            float e0 = __uint_as_float(u << 16);
            float e1 = __uint_as_float(u & 0xFFFF0000u);
            float s0 = elv + e0, s1 = elv + e1;
            s0 = fmaxf(s0, 0.2f * s0) - mxv;
            s1 = fmaxf(s1, 0.2f * s1) - mxv;
            float p0 = __expf(s0), p1 = __expf(s1);
            p0 = ((bits >> (2 * pr)) & 1u) ? p0 : 0.f;
            p1 = ((bits >> (2 * pr + 1)) & 1u) ? p1 : 0.f;
            unsigned b0 = __float_as_uint(p0) & 0xFFFF0000u;
            unsigned b1 = __float_as_uint(p1) & 0xFFFF0000u;
            ps += __uint_as_float(b0) + __uint_as_float(b1);
            au[pr] = __builtin_amdgcn_perm(__float_as_uint(p1), __float_as_uint(p0), 0x07060302u);
        }
        short8 af = __builtin_bit_cast(short8, au);
        acc[0] = __builtin_amdgcn_mfma_f32_16x16x32_bf16(af, bv0, acc[0], 0, 0, 0);
        acc[1] = __builtin_amdgcn_mfma_f32_16x16x32_bf16(af, bv1, acc[1], 0, 0, 0);
        acc[2] = __builtin_amdgcn_mfma_f32_16x16x32_bf16(af, bv2, acc[2], 0, 0, 0);
        acc[3] = __builtin_amdgcn_mfma_f32_16x16x32_bf16(af, bv3, acc[3], 0, 0, 0);
    }

    {
        float v = ps;
        v += __shfl_xor(v, 16);
        v += __shfl_xor(v, 32);
        if (q == 0) pssh[w][n] = v;
    }
#pragma unroll
    for (int ct = 0; ct < 4; ++ct)
#pragma unroll
        for (int r = 0; r < 4; ++r) osh[w][ct][q * 4 + r][n] = acc[ct][r];
    __syncthreads();

    for (int idx = t; idx < 1024; idx += 512) {
        int ct = idx >> 8, mm = (idx >> 4) & 15, nn = idx & 15;
        float o = 0.f, pv = 0.f;
#pragma unroll
        for (int ww = 0; ww < 8; ++ww) { o += osh[ww][ct][mm][nn]; pv += pssh[ww][mm]; }
        out[(size_t)(i0 + mm) * 128 + col0 + ct * 16 + nn] = o / pv;
    }
}

extern "C" void kernel_launch(void* const* d_in, const int* in_sizes, int n_in,
                              void* d_out, int out_size, void* d_ws, size_t ws_size,
                              hipStream_t stream) {
    const float* x   = (const float*)d_in[0];
    const float* W1  = (const float*)d_in[1];
    const float* a1l = (const float*)d_in[2];
    const float* a1r = (const float*)d_in[3];
    const float* W2  = (const float*)d_in[4];
    const float* a2l = (const float*)d_in[5];
    const float* a2r = (const float*)d_in[6];
    const int* adj = (const int*)d_in[7];

    char* p = (char*)d_ws;
    u16* xb    = (u16*)p;            p += (size_t)NN * 512 * 2;
    u16* w1t   = (u16*)p;            p += (size_t)256 * 512 * 2;
    u16* w2t   = (u16*)p;            p += (size_t)128 * 256 * 2;
    unsigned* abits = (unsigned*)p;  p += (size_t)NN * 64 * 4;
    u16* gbt1  = (u16*)p;            p += (size_t)256 * NN * 2;
    u16* hbb   = (u16*)p;            p += (size_t)NN * 256 * 2;
    u16* gbt2  = (u16*)p;            p += (size_t)128 * NN * 2;
    float* el1 = (float*)p;          p += (size_t)NN * 8 * 4;
    float* ert1 = (float*)p;         p += (size_t)8 * NN * 4;
    float* el2 = (float*)p;          p += (size_t)NN * 4;
    float* ert2 = (float*)p;         p += (size_t)NN * 4;

    hipMemsetAsync(el2, 0, 2 * NN * sizeof(float), stream);  // zero el2+ert2 (adjacent)
    prep<<<18048, 256, 0, stream>>>(x, W1, W2, adj, xb, w1t, w2t, (u64*)abits);

    gemm1<<<dim3(128, 8), 256, 0, stream>>>(xb, w1t, a1l, a1r, gbt1, el1, ert1);
    attn1<<<dim3(128, 4), 512, 0, stream>>>(el1, ert1, abits, gbt1, hbb);

    gemm2<<<dim3(128, 4), 256, 0, stream>>>(hbb, w2t, a2l, a2r, gbt2, el2, ert2);
    attn2<<<dim3(128, 2), 512, 0, stream>>>(el2, ert2, abits, gbt2, (float*)d_out);
}

// Round 10
// 128.933 us; speedup vs baseline: 1.0283x; 1.0283x over previous
//
#include <hip/hip_runtime.h>
#include <hip/hip_bf16.h>

#define NN 2048
typedef unsigned short u16;
typedef unsigned long long u64;
typedef __attribute__((ext_vector_type(8))) short short8;
typedef __attribute__((ext_vector_type(4))) float f32x4;

// fp32 -> bf16 bits, RNE
__device__ __forceinline__ unsigned bfb(float x) {
    unsigned u = __float_as_uint(x);
    return (u + 0x7FFFu + ((u >> 16) & 1u)) >> 16;
}
__device__ __forceinline__ unsigned pk2(float a, float b) { return bfb(a) | (bfb(b) << 16); }

// ---------------- prep: adj bitmask + bf16 conversions (x, W1^T, W2^T), one dispatch ----------------
__global__ __launch_bounds__(256) void prep(const float* __restrict__ x,
                                            const float* __restrict__ W1,
                                            const float* __restrict__ W2,
                                            const int* __restrict__ adj,
                                            u16* __restrict__ xb, u16* __restrict__ w1t,
                                            u16* __restrict__ w2t, u64* __restrict__ ab) {
    const int b = blockIdx.x;
    if (b < 16384) {                         // adj bits
        int t = b * 256 + threadIdx.x;
        int W = t >> 6, lane = t & 63;
        int i = W >> 5, jw = W & 31;
        int a = adj[(size_t)i * NN + jw * 64 + lane];
        u64 m = __ballot(a != 0);
        if (lane == 0) ab[(size_t)i * 32 + jw] = m;
    } else if (b < 16384 + 1024) {           // x: 2048x512 -> bf16
        int t = (b - 16384) * 256 + threadIdx.x;
        float4 v = ((const float4*)x)[t];
        uint2 o;
        o.x = pk2(v.x, v.y);
        o.y = pk2(v.z, v.w);
        ((uint2*)xb)[t] = o;
    } else if (b < 16384 + 1024 + 512) {     // w1t[c][k] = W1[k][c]
        int u = (b - 17408) * 256 + threadIdx.x;
        int c = u >> 9, k = u & 511;
        w1t[u] = (u16)bfb(W1[(size_t)k * 256 + c]);
    } else {                                 // w2t[c][k] = W2[k][c]
        int u = (b - 17920) * 256 + threadIdx.x;
        int c = u >> 8, k = u & 255;
        w2t[u] = (u16)bfb(W2[(size_t)k * 128 + c]);
    }
}

// ---------------- gemm1: 16 rows x 32 cols (= head cs), K-split-2; el/ert in epilogue ----------------
__global__ __launch_bounds__(256) void gemm1(const u16* __restrict__ A,   // [2048][512]
                                             const u16* __restrict__ BT,  // [256][512]
                                             const float* __restrict__ al,
                                             const float* __restrict__ ar,
                                             u16* __restrict__ GT,        // [256][2048]
                                             float* __restrict__ el,      // [2048][8]
                                             float* __restrict__ ert) {   // [8][2048]
    const int i0 = blockIdx.x * 16, cs = blockIdx.y;
    const int t = threadIdx.x, lane = t & 63, w = t >> 6;
    const int q = lane >> 4, n = lane & 15;
    const int ct = w & 1, kh = w >> 1;
    __shared__ float osh[2][16][16];
    __shared__ float pel[2][16], per_[2][16];

    const u16* ap = A + (size_t)(i0 + n) * 512 + kh * 256 + q * 8;
    const u16* bp = BT + (size_t)(cs * 32 + ct * 16 + n) * 512 + kh * 256 + q * 8;
    f32x4 acc = {0.f, 0.f, 0.f, 0.f};
#pragma unroll
    for (int ks = 0; ks < 8; ++ks) {
        short8 a = *(const short8*)(ap + ks * 32);
        short8 b = *(const short8*)(bp + ks * 32);
        acc = __builtin_amdgcn_mfma_f32_16x16x32_bf16(a, b, acc, 0, 0, 0);
    }
    if (kh == 1) {
#pragma unroll
        for (int r = 0; r < 4; ++r) osh[ct][q * 4 + r][n] = acc[r];
    }
    __syncthreads();
    if (kh == 0) {
#pragma unroll
        for (int r = 0; r < 4; ++r) acc[r] += osh[ct][q * 4 + r][n];
        uint2 g0;
        g0.x = pk2(acc[0], acc[1]);
        g0.y = pk2(acc[2], acc[3]);
        *(uint2*)&GT[(size_t)(cs * 32 + ct * 16 + n) * NN + i0 + q * 4] = g0;
        const float alv = al[ct * 16 + n], arv = ar[ct * 16 + n];
#pragma unroll
        for (int r = 0; r < 4; ++r) {
            float ve = acc[r] * alv, vr = acc[r] * arv;
#pragma unroll
            for (int off = 1; off <= 8; off <<= 1) {
                ve += __shfl_xor(ve, off);
                vr += __shfl_xor(vr, off);
            }
            if (n == 0) { pel[ct][q * 4 + r] = ve; per_[ct][q * 4 + r] = vr; }
        }
    }
    __syncthreads();
    if (t < 16) {
        el[(size_t)(i0 + t) * 8 + cs] = pel[0][t] + pel[1][t];
        ert[(size_t)cs * NN + i0 + t] = per_[0][t] + per_[1][t];
    }
}

// ---------------- gemm2: 16 rows x 32 cols of 128, K-split-2; el/ert per-cs partials (no atomics) ----------------
__global__ __launch_bounds__(256) void gemm2(const u16* __restrict__ A,   // [2048][256]
                                             const u16* __restrict__ BT,  // [128][256]
                                             const float* __restrict__ al,
                                             const float* __restrict__ ar,
                                             u16* __restrict__ GT,        // [128][2048]
                                             float* __restrict__ el2p,    // [4][2048]
                                             float* __restrict__ er2p) {  // [4][2048]
    const int i0 = blockIdx.x * 16, cs = blockIdx.y;
    const int t = threadIdx.x, lane = t & 63, w = t >> 6;
    const int q = lane >> 4, n = lane & 15;
    const int ct = w & 1, kh = w >> 1;
    __shared__ float osh[2][16][16];
    __shared__ float pel[2][16], per_[2][16];

    const u16* ap = A + (size_t)(i0 + n) * 256 + kh * 128 + q * 8;
    const u16* bp = BT + (size_t)(cs * 32 + ct * 16 + n) * 256 + kh * 128 + q * 8;
    f32x4 acc = {0.f, 0.f, 0.f, 0.f};
#pragma unroll
    for (int ks = 0; ks < 4; ++ks) {
        short8 a = *(const short8*)(ap + ks * 32);
        short8 b = *(const short8*)(bp + ks * 32);
        acc = __builtin_amdgcn_mfma_f32_16x16x32_bf16(a, b, acc, 0, 0, 0);
    }
    if (kh == 1) {
#pragma unroll
        for (int r = 0; r < 4; ++r) osh[ct][q * 4 + r][n] = acc[r];
    }
    __syncthreads();
    if (kh == 0) {
#pragma unroll
        for (int r = 0; r < 4; ++r) acc[r] += osh[ct][q * 4 + r][n];
        uint2 g0;
        g0.x = pk2(acc[0], acc[1]);
        g0.y = pk2(acc[2], acc[3]);
        *(uint2*)&GT[(size_t)(cs * 32 + ct * 16 + n) * NN + i0 + q * 4] = g0;
        const float alv = al[cs * 32 + ct * 16 + n], arv = ar[cs * 32 + ct * 16 + n];
#pragma unroll
        for (int r = 0; r < 4; ++r) {
            float ve = acc[r] * alv, vr = acc[r] * arv;
#pragma unroll
            for (int off = 1; off <= 8; off <<= 1) {
                ve += __shfl_xor(ve, off);
                vr += __shfl_xor(vr, off);
            }
            if (n == 0) { pel[ct][q * 4 + r] = ve; per_[ct][q * 4 + r] = vr; }
        }
    }
    __syncthreads();
    if (t < 16) {
        el2p[(size_t)cs * NN + i0 + t] = pel[0][t] + pel[1][t];
        er2p[(size_t)cs * NN + i0 + t] = per_[0][t] + per_[1][t];
    }
}

// ---------------- attn1: 16 rows x 2 heads (64 cols), full j, 128-j tiles, double-buffered pl ----------------
// grid (128,4) x 512 thr. staging: (m=t>>5, jq=t&31) -> 4 j x 2 heads.
// MFMA roles: hl=w>>2 (head), ch=(w>>1)&1 (col-tile), kf2=w&1 (64-j k-frag pair -> 2 MFMAs/tile).
__global__ __launch_bounds__(512) void attn1(const float* __restrict__ el,      // [2048][8]
                                             const float* __restrict__ ert,     // [8][2048]
                                             const unsigned* __restrict__ ab32, // [2048][64]
                                             const u16* __restrict__ gbt,       // [256][2048]
                                             u16* __restrict__ hbb) {           // [2048][256]
    const int rt = blockIdx.x, sec = blockIdx.y;
    const int i0 = rt * 16, h0 = sec * 2;
    const int t = threadIdx.x, lane = t & 63, w = t >> 6;
    const int q = lane >> 4, n = lane & 15;
    const int m = t >> 5, jq = t & 31;
    const int hl = w >> 2, ch = (w >> 1) & 1, kf2 = w & 1;

    __shared__ u16 ersb[2][2048];                     // bf16 er
    __shared__ __align__(16) u16 pl[2][2][16][136];   // [buf][h][m][k]
    __shared__ unsigned absh[16][64];
    __shared__ float psum_sh[16][2];
    __shared__ float osh[2][2][16][16];
    __shared__ float wmax[2][8];
    __shared__ float mxsh[2];

    float4 v0 = *(const float4*)(ert + (size_t)h0 * NN + t * 4);
    float4 v1 = *(const float4*)(ert + (size_t)(h0 + 1) * NN + t * 4);
    uint2 c0, c1;
    c0.x = pk2(v0.x, v0.y); c0.y = pk2(v0.z, v0.w);
    c1.x = pk2(v1.x, v1.y); c1.y = pk2(v1.z, v1.w);
    *(uint2*)&ersb[0][t * 4] = c0;
    *(uint2*)&ersb[1][t * 4] = c1;
    float m0 = fmaxf(fmaxf(v0.x, v0.y), fmaxf(v0.z, v0.w));
    float m1 = fmaxf(fmaxf(v1.x, v1.y), fmaxf(v1.z, v1.w));
#pragma unroll
    for (int off = 32; off; off >>= 1) {
        m0 = fmaxf(m0, __shfl_xor(m0, off));
        m1 = fmaxf(m1, __shfl_xor(m1, off));
    }
    if (lane == 0) { wmax[0][w] = m0; wmax[1][w] = m1; }
    for (int c = t; c < 1024; c += 512)
        absh[c >> 6][c & 63] = ab32[(size_t)(i0 + (c >> 6)) * 64 + (c & 63)];
    __syncthreads();
    if (t < 2) {
        float mm = wmax[t][0];
#pragma unroll
        for (int ww = 1; ww < 8; ++ww) mm = fmaxf(mm, wmax[t][ww]);
        mxsh[t] = mm;
    }
    __syncthreads();

    float elv[2], mxv[2], ps[2];
#pragma unroll
    for (int h = 0; h < 2; ++h) {
        float e = el[(size_t)(i0 + m) * 8 + h0 + h];
        elv[h] = e;
        float mm = e + mxsh[h];
        mxv[h] = fmaxf(mm, 0.2f * mm);
        ps[h] = 0.f;
    }

    auto stage = [&](int tl, int nb) {
        unsigned word = absh[m][tl * 4 + (jq >> 3)];
        unsigned bits = (word >> ((jq & 7) * 4)) & 0xFu;
        const int jo = tl * 128 + jq * 4;
        uint2 raw0 = *(const uint2*)&ersb[0][jo];
        uint2 raw1 = *(const uint2*)&ersb[1][jo];
#pragma unroll
        for (int h = 0; h < 2; ++h) {
            uint2 raw = h ? raw1 : raw0;
            float e0 = __uint_as_float(raw.x << 16);
            float e1 = __uint_as_float(raw.x & 0xFFFF0000u);
            float e2 = __uint_as_float(raw.y << 16);
            float e3 = __uint_as_float(raw.y & 0xFFFF0000u);
            float s0 = elv[h] + e0, s1 = elv[h] + e1, s2 = elv[h] + e2, s3 = elv[h] + e3;
            s0 = fmaxf(s0, 0.2f * s0) - mxv[h];
            s1 = fmaxf(s1, 0.2f * s1) - mxv[h];
            s2 = fmaxf(s2, 0.2f * s2) - mxv[h];
            s3 = fmaxf(s3, 0.2f * s3) - mxv[h];
            float p0 = (bits & 1u) ? __expf(s0) : 0.f;
            float p1 = (bits & 2u) ? __expf(s1) : 0.f;
            float p2 = (bits & 4u) ? __expf(s2) : 0.f;
            float p3 = (bits & 8u) ? __expf(s3) : 0.f;
            ps[h] += (p0 + p1) + (p2 + p3);
            uint2 pkv;
            pkv.x = pk2(p0, p1);
            pkv.y = pk2(p2, p3);
            *(uint2*)&pl[nb][h][m][jq * 4] = pkv;
        }
    };

    const int col = sec * 64 + hl * 32 + ch * 16 + n;
    const u16* gb = gbt + (size_t)col * NN + kf2 * 64 + q * 8;
    short8 bc0 = *(const short8*)gb;
    short8 bc1 = *(const short8*)(gb + 32);
    f32x4 acc = {0.f, 0.f, 0.f, 0.f};

    stage(0, 0);
    __syncthreads();

    for (int tile = 0; tile < 16; ++tile) {
        short8 bn0 = bc0, bn1 = bc1;
        if (tile < 15) {
            bn0 = *(const short8*)(gb + tile * 128 + 128);
            bn1 = *(const short8*)(gb + tile * 128 + 160);
        }
        const u16* ap = &pl[tile & 1][hl][n][kf2 * 64 + q * 8];
        short8 a0 = *(const short8*)ap;
        short8 a1 = *(const short8*)(ap + 32);
        acc = __builtin_amdgcn_mfma_f32_16x16x32_bf16(a0, bc0, acc, 0, 0, 0);
        acc = __builtin_amdgcn_mfma_f32_16x16x32_bf16(a1, bc1, acc, 0, 0, 0);
        if (tile < 15) stage(tile + 1, (tile + 1) & 1);
        bc0 = bn0; bc1 = bn1;
        __syncthreads();
    }

#pragma unroll
    for (int h = 0; h < 2; ++h) {
        float v = ps[h];
#pragma unroll
        for (int off = 16; off; off >>= 1) v += __shfl_down(v, off, 32);
        if (jq == 0) psum_sh[m][h] = v;
    }
    if (kf2 == 1) {
#pragma unroll
        for (int r = 0; r < 4; ++r) osh[hl][ch][q * 4 + r][n] = acc[r];
    }
    __syncthreads();
    if (kf2 == 0) {
#pragma unroll
        for (int r = 0; r < 4; ++r) {
            int mr = q * 4 + r;
            float o = (acc[r] + osh[hl][ch][mr][n]) / psum_sh[mr][hl];
            o = o > 0.f ? o : (__expf(o) - 1.f); // ELU
            hbb[(size_t)(i0 + mr) * 256 + col] = (u16)bfb(o);
        }
    }
}

// ---------------- attn2: 16 rows x 64 cols (1 head), full j, 128-j tiles, double-buffered ----------------
// grid (128,2) x 512 thr. el/er arrive as 4 per-cs partial slices; summed during staging.
__global__ __launch_bounds__(512) void attn2(const float* __restrict__ el2p,    // [4][2048]
                                             const float* __restrict__ er2p,    // [4][2048]
                                             const unsigned* __restrict__ ab32,
                                             const u16* __restrict__ gbt,       // [128][2048]
                                             float* __restrict__ out) {         // [2048][128]
    const int rt = blockIdx.x, sec = blockIdx.y;
    const int i0 = rt * 16;
    const int t = threadIdx.x, lane = t & 63, w = t >> 6;
    const int q = lane >> 4, n = lane & 15;
    const int m = t >> 5, jq = t & 31;
    const int ct = w >> 1, kf2 = w & 1;

    __shared__ u16 ersb[2048];
    __shared__ __align__(16) u16 pl[2][16][136];
    __shared__ unsigned absh[16][64];
    __shared__ float psum_sh[16];
    __shared__ float osh[4][16][16];
    __shared__ float wmax[8];
    __shared__ float mxsh;

    float4 a0 = *(const float4*)(er2p + t * 4);
    float4 a1 = *(const float4*)(er2p + NN + t * 4);
    float4 a2 = *(const float4*)(er2p + 2 * NN + t * 4);
    float4 a3 = *(const float4*)(er2p + 3 * NN + t * 4);
    float4 v0;
    v0.x = ((a0.x + a1.x) + (a2.x + a3.x));
    v0.y = ((a0.y + a1.y) + (a2.y + a3.y));
    v0.z = ((a0.z + a1.z) + (a2.z + a3.z));
    v0.w = ((a0.w + a1.w) + (a2.w + a3.w));
    uint2 c0;
    c0.x = pk2(v0.x, v0.y); c0.y = pk2(v0.z, v0.w);
    *(uint2*)&ersb[t * 4] = c0;
    float m0 = fmaxf(fmaxf(v0.x, v0.y), fmaxf(v0.z, v0.w));
#pragma unroll
    for (int off = 32; off; off >>= 1) m0 = fmaxf(m0, __shfl_xor(m0, off));
    if (lane == 0) wmax[w] = m0;
    for (int c = t; c < 1024; c += 512)
        absh[c >> 6][c & 63] = ab32[(size_t)(i0 + (c >> 6)) * 64 + (c & 63)];
    __syncthreads();
    if (t == 0) {
        float mm = wmax[0];
#pragma unroll
        for (int ww = 1; ww < 8; ++ww) mm = fmaxf(mm, wmax[ww]);
        mxsh = mm;
    }
    __syncthreads();

    const float elv = el2p[i0 + m] + el2p[NN + i0 + m] + el2p[2 * NN + i0 + m] + el2p[3 * NN + i0 + m];
    float mm2 = elv + mxsh;
    const float mxv = fmaxf(mm2, 0.2f * mm2);
    float ps = 0.f;

    auto stage = [&](int tl, int nb) {
        unsigned word = absh[m][tl * 4 + (jq >> 3)];
        unsigned bits = (word >> ((jq & 7) * 4)) & 0xFu;
        const int jo = tl * 128 + jq * 4;
        uint2 raw = *(const uint2*)&ersb[jo];
        float e0 = __uint_as_float(raw.x << 16);
        float e1 = __uint_as_float(raw.x & 0xFFFF0000u);
        float e2 = __uint_as_float(raw.y << 16);
        float e3 = __uint_as_float(raw.y & 0xFFFF0000u);
        float s0 = elv + e0, s1 = elv + e1, s2 = elv + e2, s3 = elv + e3;
        s0 = fmaxf(s0, 0.2f * s0) - mxv;
        s1 = fmaxf(s1, 0.2f * s1) - mxv;
        s2 = fmaxf(s2, 0.2f * s2) - mxv;
        s3 = fmaxf(s3, 0.2f * s3) - mxv;
        float p0 = (bits & 1u) ? __expf(s0) : 0.f;
        float p1 = (bits & 2u) ? __expf(s1) : 0.f;
        float p2 = (bits & 4u) ? __expf(s2) : 0.f;
        float p3 = (bits & 8u) ? __expf(s3) : 0.f;
        ps += (p0 + p1) + (p2 + p3);
        uint2 pkv;
        pkv.x = pk2(p0, p1);
        pkv.y = pk2(p2, p3);
        *(uint2*)&pl[nb][m][jq * 4] = pkv;
    };

    const int col = sec * 64 + ct * 16 + n;
    const u16* gb = gbt + (size_t)col * NN + kf2 * 64 + q * 8;
    short8 bc0 = *(const short8*)gb;
    short8 bc1 = *(const short8*)(gb + 32);
    f32x4 acc = {0.f, 0.f, 0.f, 0.f};

    stage(0, 0);
    __syncthreads();

    for (int tile = 0; tile < 16; ++tile) {
        short8 bn0 = bc0, bn1 = bc1;
        if (tile < 15) {
            bn0 = *(const short8*)(gb + tile * 128 + 128);
            bn1 = *(const short8*)(gb + tile * 128 + 160);
        }
        const u16* ap = &pl[tile & 1][n][kf2 * 64 + q * 8];
        short8 a0v = *(const short8*)ap;
        short8 a1v = *(const short8*)(ap + 32);
        acc = __builtin_amdgcn_mfma_f32_16x16x32_bf16(a0v, bc0, acc, 0, 0, 0);
        acc = __builtin_amdgcn_mfma_f32_16x16x32_bf16(a1v, bc1, acc, 0, 0, 0);
        if (tile < 15) stage(tile + 1, (tile + 1) & 1);
        bc0 = bn0; bc1 = bn1;
        __syncthreads();
    }

#pragma unroll
    for (int off = 16; off; off >>= 1) ps += __shfl_down(ps, off, 32);
    if (jq == 0) psum_sh[m] = ps;
    if (kf2 == 1) {
#pragma unroll
        for (int r = 0; r < 4; ++r) osh[ct][q * 4 + r][n] = acc[r];
    }
    __syncthreads();
    if (kf2 == 0) {
#pragma unroll
        for (int r = 0; r < 4; ++r) {
            int mr = q * 4 + r;
            out[(size_t)(i0 + mr) * 128 + col] = (acc[r] + osh[ct][mr][n]) / psum_sh[mr];
        }
    }
}

extern "C" void kernel_launch(void* const* d_in, const int* in_sizes, int n_in,
                              void* d_out, int out_size, void* d_ws, size_t ws_size,
                              hipStream_t stream) {
    const float* x   = (const float*)d_in[0];
    const float* W1  = (const float*)d_in[1];
    const float* a1l = (const float*)d_in[2];
    const float* a1r = (const float*)d_in[3];
    const float* W2  = (const float*)d_in[4];
    const float* a2l = (const float*)d_in[5];
    const float* a2r = (const float*)d_in[6];
    const int* adj = (const int*)d_in[7];

    char* p = (char*)d_ws;
    u16* xb    = (u16*)p;            p += (size_t)NN * 512 * 2;
    u16* w1t   = (u16*)p;            p += (size_t)256 * 512 * 2;
    u16* w2t   = (u16*)p;            p += (size_t)128 * 256 * 2;
    unsigned* abits = (unsigned*)p;  p += (size_t)NN * 64 * 4;
    u16* gbt1  = (u16*)p;            p += (size_t)256 * NN * 2;
    u16* hbb   = (u16*)p;            p += (size_t)NN * 256 * 2;
    u16* gbt2  = (u16*)p;            p += (size_t)128 * NN * 2;
    float* el1 = (float*)p;          p += (size_t)NN * 8 * 4;
    float* ert1 = (float*)p;         p += (size_t)8 * NN * 4;
    float* el2p = (float*)p;         p += (size_t)4 * NN * 4;
    float* er2p = (float*)p;         p += (size_t)4 * NN * 4;

    prep<<<18048, 256, 0, stream>>>(x, W1, W2, adj, xb, w1t, w2t, (u64*)abits);

    gemm1<<<dim3(128, 8), 256, 0, stream>>>(xb, w1t, a1l, a1r, gbt1, el1, ert1);
    attn1<<<dim3(128, 4), 512, 0, stream>>>(el1, ert1, abits, gbt1, hbb);

    gemm2<<<dim3(128, 4), 256, 0, stream>>>(hbb, w2t, a2l, a2r, gbt2, el2p, er2p);
    attn2<<<dim3(128, 2), 512, 0, stream>>>(el2p, er2p, abits, gbt2, (float*)d_out);
}